// Round 1
// baseline (307.416 us; speedup 1.0000x reference)
//
#include <hip/hip_runtime.h>
#include <math.h>

// ---------------------------------------------------------------------------
// HashGrid INR fused kernel for MI355X (gfx950)
//   prep_pack : weights -> fragment-major bf16 hi/lo packs in d_ws
//   inr_main  : encode (hash grid) + 4 MFMA layers (bf16x3 split) + final dot
// ---------------------------------------------------------------------------

typedef __bf16 bf16x8 __attribute__((ext_vector_type(8)));
typedef float  f32x4  __attribute__((ext_vector_type(4)));
typedef unsigned int u32x4 __attribute__((ext_vector_type(4)));

struct LevelParams { float res[16]; unsigned int hsize[16]; };

static constexpr int MTILE = 128;        // points per block
static constexpr int LDA   = 264;        // padded activation row stride (elems)
static constexpr int ACT_ELEMS = MTILE * LDA;
// pack units: L0: 32 (S=2 x 16 ct), L1..L3: 128 each. unit = 2048 B = 1024 shorts
static constexpr int UNITS_L0 = 32;
static constexpr int UB_L0 = 0, UB_L1 = 32, UB_L2 = 160, UB_L3 = 288;
static constexpr int UNITS_TOTAL = 416;

__device__ __forceinline__ unsigned short f32_to_bf16_rne(float f) {
  unsigned u = __float_as_uint(f);
  unsigned r = (u + 0x7fffu + ((u >> 16) & 1u)) >> 16;
  return (unsigned short)r;
}
__device__ __forceinline__ float bf16_bits_to_f32(unsigned short h) {
  return __uint_as_float(((unsigned)h) << 16);
}
__device__ __forceinline__ void split_store(unsigned short* ahi, unsigned short* alo,
                                            int idx, float v) {
  unsigned short h = f32_to_bf16_rne(v);
  float hf = bf16_bits_to_f32(h);
  unsigned short lo = f32_to_bf16_rne(v - hf);
  ahi[idx] = h;
  alo[idx] = lo;
}

// --------------------------- weight packing --------------------------------
// Layout per unit (kstep s, coltile ct): [2][64 lanes][8 elems] bf16
//   hi at lane*8+e, lo at 512+lane*8+e.
// Fragment k-mapping (consistent for A and B, bijective per k-step):
//   k = 32*s + 8*(lane>>4) + e ; col = 16*ct + (lane&15)
__global__ void prep_pack(const float* __restrict__ W0, const float* __restrict__ W1,
                          const float* __restrict__ W2, const float* __restrict__ W3,
                          unsigned short* __restrict__ pack) {
  int b = blockIdx.x;          // 0..415 == unit index
  int lane = threadIdx.x;      // 0..63
  const float* W; int K; int r;
  if (b < UNITS_L0) { W = W0; K = 33; r = b; }
  else {
    int b2 = b - UNITS_L0; int ly = b2 >> 7; r = b2 & 127;
    W = (ly == 0) ? W1 : (ly == 1) ? W2 : W3; K = 256;
  }
  int s = r >> 4, ct = r & 15;
  int col   = (ct << 4) + (lane & 15);
  int kbase = (s << 5) + ((lane >> 4) << 3);
  unsigned short* dst = pack + (size_t)b * 1024;
#pragma unroll
  for (int e = 0; e < 8; ++e) {
    int k = kbase + e;
    float v = (k < K) ? W[k * 256 + col] : 0.0f;
    unsigned short h = f32_to_bf16_rne(v);
    float hf = bf16_bits_to_f32(h);
    unsigned short lo = f32_to_bf16_rne(v - hf);
    dst[lane * 8 + e]       = h;
    dst[512 + lane * 8 + e] = lo;
  }
}

// ------------------------------ main kernel --------------------------------
__device__ __forceinline__ void run_layer(unsigned short* ahi, unsigned short* alo,
                                          const unsigned short* __restrict__ pack,
                                          int unitbase, int S,
                                          const float* __restrict__ bias,
                                          int wr, int wc, int lm, int lg, int lane) {
  f32x4 acc[4][4];
#pragma unroll
  for (int i = 0; i < 4; ++i)
#pragma unroll
    for (int j = 0; j < 4; ++j) acc[i][j] = (f32x4)0.0f;

  for (int s = 0; s < S; ++s) {
    bf16x8 a_h[4], a_l[4], b_h[4], b_l[4];
#pragma unroll
    for (int rt = 0; rt < 4; ++rt) {
      int row = (wr << 6) + (rt << 4) + lm;
      int off = row * LDA + (s << 5) + (lg << 3);
      u32x4 th = *(const u32x4*)(ahi + off);
      u32x4 tl = *(const u32x4*)(alo + off);
      a_h[rt] = __builtin_bit_cast(bf16x8, th);
      a_l[rt] = __builtin_bit_cast(bf16x8, tl);
    }
#pragma unroll
    for (int ct = 0; ct < 4; ++ct) {
      int unit = unitbase + (s << 4) + (wc << 2) + ct;
      const unsigned short* bp = pack + (size_t)unit * 1024 + (lane << 3);
      u32x4 th = *(const u32x4*)(bp);
      u32x4 tl = *(const u32x4*)(bp + 512);
      b_h[ct] = __builtin_bit_cast(bf16x8, th);
      b_l[ct] = __builtin_bit_cast(bf16x8, tl);
    }
#pragma unroll
    for (int rt = 0; rt < 4; ++rt)
#pragma unroll
      for (int ct = 0; ct < 4; ++ct) {
        acc[rt][ct] = __builtin_amdgcn_mfma_f32_16x16x32_bf16(a_h[rt], b_h[ct], acc[rt][ct], 0, 0, 0);
        acc[rt][ct] = __builtin_amdgcn_mfma_f32_16x16x32_bf16(a_l[rt], b_h[ct], acc[rt][ct], 0, 0, 0);
        acc[rt][ct] = __builtin_amdgcn_mfma_f32_16x16x32_bf16(a_h[rt], b_l[ct], acc[rt][ct], 0, 0, 0);
      }
  }
  __syncthreads();   // all reads of act done -> safe to overwrite
#pragma unroll
  for (int ct = 0; ct < 4; ++ct) {
    int col = (((wc << 2) + ct) << 4) + lm;
    float bv = bias[col];
#pragma unroll
    for (int rt = 0; rt < 4; ++rt) {
#pragma unroll
      for (int r = 0; r < 4; ++r) {
        int row = (wr << 6) + (rt << 4) + (lg << 2) + r;
        float v = acc[rt][ct][r] + bv;
        v = fmaxf(v, 0.0f);
        split_store(ahi, alo, row * LDA + col, v);
      }
    }
  }
  __syncthreads();
}

__global__ __launch_bounds__(512, 1) void inr_main(
    const float* __restrict__ x, const float* __restrict__ tables,
    const float* __restrict__ b0, const float* __restrict__ b1,
    const float* __restrict__ b2, const float* __restrict__ b3,
    const float* __restrict__ W4, const float* __restrict__ b4,
    const unsigned short* __restrict__ pack, float* __restrict__ out,
    LevelParams P) {
  extern __shared__ char smem[];
  unsigned short* ahi = (unsigned short*)smem;
  unsigned short* alo = ahi + ACT_ELEMS;
  float* w4s = (float*)(alo + ACT_ELEMS);

  const int tid = threadIdx.x;
  if (tid < 256) w4s[tid] = W4[tid];

  // ---------------- encode: 4 threads/point, 4 levels/thread ----------------
  {
    int pl = tid >> 2, q = tid & 3;
    size_t p = (size_t)blockIdx.x * MTILE + pl;
    float x0 = x[3 * p + 0], x1 = x[3 * p + 1], x2 = x[3 * p + 2];
#pragma unroll
    for (int j = 0; j < 4; ++j) {
      int l = (q << 2) + j;
      float rf = P.res[l];
      unsigned hs = P.hsize[l];
      float xs0 = x0 * rf, xs1 = x1 * rf;
      float fl0 = floorf(xs0), fl1 = floorf(xs1);
      float f0 = xs0 - fl0, f1 = xs1 - fl1;
      int i0 = (int)fl0, i1 = (int)fl1;
      unsigned ua0 = (unsigned)i0, ua1 = (unsigned)(i0 + 1);
      unsigned vb0 = (unsigned)i1 * 2654435761u;
      unsigned vb1 = (unsigned)(i1 + 1) * 2654435761u;
      const float* tl = tables + ((size_t)l << 13);  // l * 4096 * 2
      float g0 = 1.0f - f0, g1 = 1.0f - f1;
      float acc0 = 0.0f, acc1 = 0.0f;
      { unsigned h = (ua0 ^ vb0) % hs; float w = g0 * g1; acc0 += w * tl[2*h]; acc1 += w * tl[2*h+1]; }
      { unsigned h = (ua0 ^ vb1) % hs; float w = g0 * f1; acc0 += w * tl[2*h]; acc1 += w * tl[2*h+1]; }
      { unsigned h = (ua1 ^ vb0) % hs; float w = f0 * g1; acc0 += w * tl[2*h]; acc1 += w * tl[2*h+1]; }
      { unsigned h = (ua1 ^ vb1) % hs; float w = f0 * f1; acc0 += w * tl[2*h]; acc1 += w * tl[2*h+1]; }
      int base = pl * LDA + (l << 1);
      split_store(ahi, alo, base, acc0);
      split_store(ahi, alo, base + 1, acc1);
    }
    // features 32..63: [x2, zeros...]
    int cb = 32 + (q << 3);
#pragma unroll
    for (int e = 0; e < 8; ++e) {
      int col = cb + e;
      float v = (col == 32) ? x2 : 0.0f;
      split_store(ahi, alo, pl * LDA + col, v);
    }
  }
  __syncthreads();

  const int lane = tid & 63;
  const int w = tid >> 6;
  const int wr = w >> 2, wc = w & 3;
  const int lm = lane & 15, lg = lane >> 4;

  run_layer(ahi, alo, pack, UB_L0, 2, b0, wr, wc, lm, lg, lane);
  run_layer(ahi, alo, pack, UB_L1, 8, b1, wr, wc, lm, lg, lane);
  run_layer(ahi, alo, pack, UB_L2, 8, b2, wr, wc, lm, lg, lane);
  run_layer(ahi, alo, pack, UB_L3, 8, b3, wr, wc, lm, lg, lane);

  // ---------------- final layer: 256 -> 1 (VALU dot) ----------------
  {
    int pl = tid >> 2, q = tid & 3;
    const unsigned short* hrow = ahi + pl * LDA + (q << 6);
    const unsigned short* lrow = alo + pl * LDA + (q << 6);
    const float* w4p = w4s + (q << 6);
    float sum = 0.0f;
#pragma unroll
    for (int k = 0; k < 64; ++k) {
      float v = bf16_bits_to_f32(hrow[k]) + bf16_bits_to_f32(lrow[k]);
      sum = fmaf(v, w4p[k], sum);
    }
    sum += __shfl_xor(sum, 1);
    sum += __shfl_xor(sum, 2);
    if (q == 0) out[(size_t)blockIdx.x * MTILE + pl] = sum + b4[0];
  }
}

// ------------------------------- launcher ----------------------------------
extern "C" void kernel_launch(void* const* d_in, const int* in_sizes, int n_in,
                              void* d_out, int out_size, void* d_ws, size_t ws_size,
                              hipStream_t stream) {
  const float* x      = (const float*)d_in[0];
  const float* tables = (const float*)d_in[1];
  const float* W0 = (const float*)d_in[2];  const float* b0 = (const float*)d_in[3];
  const float* W1 = (const float*)d_in[4];  const float* b1 = (const float*)d_in[5];
  const float* W2 = (const float*)d_in[6];  const float* b2 = (const float*)d_in[7];
  const float* W3 = (const float*)d_in[8];  const float* b3 = (const float*)d_in[9];
  const float* W4 = (const float*)d_in[10]; const float* b4 = (const float*)d_in[11];
  unsigned short* pack = (unsigned short*)d_ws;
  float* out = (float*)d_out;

  // replicate numpy's level params with host libm doubles
  LevelParams P;
  double bgrow = exp((log(512.0) - log(8.0)) / 15.0);
  for (int l = 0; l < 16; ++l) {
    double r = floor(8.0 * pow(bgrow, (double)l));
    P.res[l] = (float)r;
    double hsd = r * r;
    if (hsd > 4096.0) hsd = 4096.0;
    P.hsize[l] = (unsigned)hsd;
  }

  prep_pack<<<UNITS_TOTAL, 64, 0, stream>>>(W0, W1, W2, W3, pack);

  size_t smem_bytes = (size_t)ACT_ELEMS * 2 * 2 + 256 * sizeof(float);  // 136192
  hipFuncSetAttribute(reinterpret_cast<const void*>(inr_main),
                      hipFuncAttributeMaxDynamicSharedMemorySize, (int)smem_bytes);

  int nblocks = out_size / MTILE;  // 262144/128 = 2048
  inr_main<<<nblocks, 512, smem_bytes, stream>>>(x, tables, b0, b1, b2, b3, W4, b4,
                                                 pack, out, P);
}

// Round 2
// 288.247 us; speedup vs baseline: 1.0665x; 1.0665x over previous
//
#include <hip/hip_runtime.h>
#include <math.h>

// ---------------------------------------------------------------------------
// HashGrid INR fused kernel for MI355X (gfx950) — round 2
//   prep_pack : weights -> fragment-major bf16 hi/lo packs in d_ws (unchanged)
//   inr_main  : MTILE=64, 2 blocks/CU; A=weights B=acts (vectorized epilogue);
//               b128 final dot.
// ---------------------------------------------------------------------------

typedef __bf16 bf16x8 __attribute__((ext_vector_type(8)));
typedef float  f32x4  __attribute__((ext_vector_type(4)));
typedef unsigned int u32x4 __attribute__((ext_vector_type(4)));
typedef unsigned int u32x2 __attribute__((ext_vector_type(2)));

struct LevelParams { float res[16]; unsigned int hsize[16]; };

static constexpr int MTILE = 64;         // points per block
static constexpr int LDA   = 264;        // padded activation row stride (elems)
static constexpr int ACT_ELEMS = MTILE * LDA;   // 16896
// pack units: L0: 32 (S=2 x 16 ct), L1..L3: 128 each. unit = 2048 B = 1024 shorts
static constexpr int UNITS_L0 = 32;
static constexpr int UB_L0 = 0, UB_L1 = 32, UB_L2 = 160, UB_L3 = 288;
static constexpr int UNITS_TOTAL = 416;

__device__ __forceinline__ unsigned short f32_to_bf16_rne(float f) {
  unsigned u = __float_as_uint(f);
  unsigned r = (u + 0x7fffu + ((u >> 16) & 1u)) >> 16;
  return (unsigned short)r;
}
__device__ __forceinline__ float bf16_bits_to_f32(unsigned u16bits) {
  return __uint_as_float(u16bits << 16);
}

// --------------------------- weight packing --------------------------------
// Layout per unit (kstep s, coltile ct): [2][64 lanes][8 elems] bf16
//   hi at lane*8+e, lo at 512+lane*8+e.
// Fragment mapping (consistent A/B k-mapping):
//   p = lane&15 (-> out column), k = 32*s + 8*(lane>>4) + e
__global__ void prep_pack(const float* __restrict__ W0, const float* __restrict__ W1,
                          const float* __restrict__ W2, const float* __restrict__ W3,
                          unsigned short* __restrict__ pack) {
  int b = blockIdx.x;          // 0..415 == unit index
  int lane = threadIdx.x;      // 0..63
  const float* W; int K; int r;
  if (b < UNITS_L0) { W = W0; K = 33; r = b; }
  else {
    int b2 = b - UNITS_L0; int ly = b2 >> 7; r = b2 & 127;
    W = (ly == 0) ? W1 : (ly == 1) ? W2 : W3; K = 256;
  }
  int s = r >> 4, ct = r & 15;
  int col   = (ct << 4) + (lane & 15);
  int kbase = (s << 5) + ((lane >> 4) << 3);
  unsigned short* dst = pack + (size_t)b * 1024;
#pragma unroll
  for (int e = 0; e < 8; ++e) {
    int k = kbase + e;
    float v = (k < K) ? W[k * 256 + col] : 0.0f;
    unsigned u = __float_as_uint(v);
    unsigned short h = (unsigned short)(u >> 16);            // truncation hi
    float hf = bf16_bits_to_f32(u >> 16);
    unsigned short lo = f32_to_bf16_rne(v - hf);
    dst[lane * 8 + e]       = h;
    dst[512 + lane * 8 + e] = lo;
  }
}

// ------------------------------ layer body ---------------------------------
// wave wc handles cols [wc*32, wc*32+32), all 64 points.
// A operand = weights (p->out col), B operand = activations (p->point).
// D: col(lane&15)=point, row(4*(lane>>4)+r)=out col  -> 4 consecutive cols/lane.
__device__ __forceinline__ void run_layer(unsigned short* ahi, unsigned short* alo,
                                          const unsigned short* __restrict__ pack,
                                          int unitbase, int S,
                                          const float* __restrict__ bias,
                                          int wc, int lm, int lg, int lane) {
  f32x4 acc[4][2];
#pragma unroll
  for (int i = 0; i < 4; ++i)
#pragma unroll
    for (int j = 0; j < 2; ++j) acc[i][j] = (f32x4)0.0f;

  for (int s = 0; s < S; ++s) {
    bf16x8 w_h[2], w_l[2], a_h[4], a_l[4];
#pragma unroll
    for (int ct = 0; ct < 2; ++ct) {
      int unit = unitbase + (s << 4) + (wc << 1) + ct;
      const unsigned short* bp = pack + (size_t)unit * 1024 + (lane << 3);
      w_h[ct] = __builtin_bit_cast(bf16x8, *(const u32x4*)(bp));
      w_l[ct] = __builtin_bit_cast(bf16x8, *(const u32x4*)(bp + 512));
    }
#pragma unroll
    for (int pt = 0; pt < 4; ++pt) {
      int off = ((pt << 4) + lm) * LDA + (s << 5) + (lg << 3);
      a_h[pt] = __builtin_bit_cast(bf16x8, *(const u32x4*)(ahi + off));
      a_l[pt] = __builtin_bit_cast(bf16x8, *(const u32x4*)(alo + off));
    }
#pragma unroll
    for (int pt = 0; pt < 4; ++pt)
#pragma unroll
      for (int ct = 0; ct < 2; ++ct) {
        acc[pt][ct] = __builtin_amdgcn_mfma_f32_16x16x32_bf16(w_h[ct], a_h[pt], acc[pt][ct], 0, 0, 0);
        acc[pt][ct] = __builtin_amdgcn_mfma_f32_16x16x32_bf16(w_l[ct], a_h[pt], acc[pt][ct], 0, 0, 0);
        acc[pt][ct] = __builtin_amdgcn_mfma_f32_16x16x32_bf16(w_h[ct], a_l[pt], acc[pt][ct], 0, 0, 0);
      }
  }
  __syncthreads();   // all reads of act done -> safe to overwrite
#pragma unroll
  for (int pt = 0; pt < 4; ++pt)
#pragma unroll
    for (int ct = 0; ct < 2; ++ct) {
      int colbase = (((wc << 1) + ct) << 4) + (lg << 2);
      float4 bv = *(const float4*)(bias + colbase);
      int base = ((pt << 4) + lm) * LDA + colbase;
      float v0 = fmaxf(acc[pt][ct][0] + bv.x, 0.0f);
      float v1 = fmaxf(acc[pt][ct][1] + bv.y, 0.0f);
      float v2 = fmaxf(acc[pt][ct][2] + bv.z, 0.0f);
      float v3 = fmaxf(acc[pt][ct][3] + bv.w, 0.0f);
      unsigned u0 = __float_as_uint(v0), u1 = __float_as_uint(v1);
      unsigned u2 = __float_as_uint(v2), u3 = __float_as_uint(v3);
      u32x2 hw = { (u0 >> 16) | (u1 & 0xffff0000u),
                   (u2 >> 16) | (u3 & 0xffff0000u) };
      float l0 = v0 - bf16_bits_to_f32(u0 >> 16);
      float l1 = v1 - bf16_bits_to_f32(u1 >> 16);
      float l2 = v2 - bf16_bits_to_f32(u2 >> 16);
      float l3 = v3 - bf16_bits_to_f32(u3 >> 16);
      u32x2 lw = { (unsigned)f32_to_bf16_rne(l0) | ((unsigned)f32_to_bf16_rne(l1) << 16),
                   (unsigned)f32_to_bf16_rne(l2) | ((unsigned)f32_to_bf16_rne(l3) << 16) };
      *(u32x2*)(ahi + base) = hw;
      *(u32x2*)(alo + base) = lw;
    }
  __syncthreads();
}

// ------------------------------ main kernel --------------------------------
__global__ __launch_bounds__(512, 4) void inr_main(
    const float* __restrict__ x, const float* __restrict__ tables,
    const float* __restrict__ b0, const float* __restrict__ b1,
    const float* __restrict__ b2, const float* __restrict__ b3,
    const float* __restrict__ W4, const float* __restrict__ b4,
    const unsigned short* __restrict__ pack, float* __restrict__ out,
    LevelParams P) {
  extern __shared__ char smem[];
  unsigned short* ahi = (unsigned short*)smem;
  unsigned short* alo = ahi + ACT_ELEMS;

  const int tid = threadIdx.x;

  // ---------------- encode: 8 threads/point, 2 levels/thread ----------------
  {
    int pl = tid >> 3, q = tid & 7;
    size_t p = (size_t)blockIdx.x * MTILE + pl;
    float x0 = x[3 * p + 0], x1 = x[3 * p + 1], x2 = x[3 * p + 2];
    float feat[4];
#pragma unroll
    for (int j = 0; j < 2; ++j) {
      int l = (q << 1) + j;
      float rf = P.res[l];
      unsigned hs = P.hsize[l];
      float xs0 = x0 * rf, xs1 = x1 * rf;
      float fl0 = floorf(xs0), fl1 = floorf(xs1);
      float f0 = xs0 - fl0, f1 = xs1 - fl1;
      int i0 = (int)fl0, i1 = (int)fl1;
      unsigned ua0 = (unsigned)i0, ua1 = (unsigned)(i0 + 1);
      unsigned vb0 = (unsigned)i1 * 2654435761u;
      unsigned vb1 = (unsigned)(i1 + 1) * 2654435761u;
      const float* tl = tables + ((size_t)l << 13);  // l * 4096 * 2
      float g0 = 1.0f - f0, g1 = 1.0f - f1;
      float acc0 = 0.0f, acc1 = 0.0f;
      unsigned e0 = ua0 ^ vb0, e1 = ua0 ^ vb1, e2 = ua1 ^ vb0, e3 = ua1 ^ vb1;
      unsigned h0, h1, h2, h3;
      if (hs == 4096u) { h0 = e0 & 4095u; h1 = e1 & 4095u; h2 = e2 & 4095u; h3 = e3 & 4095u; }
      else             { h0 = e0 % hs;    h1 = e1 % hs;    h2 = e2 % hs;    h3 = e3 % hs; }
      { float w = g0 * g1; acc0 += w * tl[2*h0]; acc1 += w * tl[2*h0+1]; }
      { float w = g0 * f1; acc0 += w * tl[2*h1]; acc1 += w * tl[2*h1+1]; }
      { float w = f0 * g1; acc0 += w * tl[2*h2]; acc1 += w * tl[2*h2+1]; }
      { float w = f0 * f1; acc0 += w * tl[2*h3]; acc1 += w * tl[2*h3+1]; }
      feat[2*j] = acc0; feat[2*j+1] = acc1;
    }
    // store features: cols 4q..4q+3 (hi/lo packed b64)
    {
      int base = pl * LDA + (q << 2);
      unsigned u0 = __float_as_uint(feat[0]), u1 = __float_as_uint(feat[1]);
      unsigned u2 = __float_as_uint(feat[2]), u3 = __float_as_uint(feat[3]);
      u32x2 hw = { (u0 >> 16) | (u1 & 0xffff0000u), (u2 >> 16) | (u3 & 0xffff0000u) };
      float l0 = feat[0] - bf16_bits_to_f32(u0 >> 16);
      float l1 = feat[1] - bf16_bits_to_f32(u1 >> 16);
      float l2 = feat[2] - bf16_bits_to_f32(u2 >> 16);
      float l3 = feat[3] - bf16_bits_to_f32(u3 >> 16);
      u32x2 lw = { (unsigned)f32_to_bf16_rne(l0) | ((unsigned)f32_to_bf16_rne(l1) << 16),
                   (unsigned)f32_to_bf16_rne(l2) | ((unsigned)f32_to_bf16_rne(l3) << 16) };
      *(u32x2*)(ahi + base) = hw;
      *(u32x2*)(alo + base) = lw;
    }
    // tail: cols 32+4q .. 35+4q : [x2, 0, 0, ...]
    {
      int base = pl * LDA + 32 + (q << 2);
      if (q == 0) {
        unsigned u0 = __float_as_uint(x2);
        u32x2 hw = { u0 >> 16, 0u };
        float l0 = x2 - bf16_bits_to_f32(u0 >> 16);
        u32x2 lw = { (unsigned)f32_to_bf16_rne(l0), 0u };
        *(u32x2*)(ahi + base) = hw;
        *(u32x2*)(alo + base) = lw;
      } else {
        u32x2 z = { 0u, 0u };
        *(u32x2*)(ahi + base) = z;
        *(u32x2*)(alo + base) = z;
      }
    }
  }
  __syncthreads();

  const int lane = tid & 63;
  const int wc = tid >> 6;          // 8 waves: each owns 32 output cols
  const int lm = lane & 15, lg = lane >> 4;

  run_layer(ahi, alo, pack, UB_L0, 2, b0, wc, lm, lg, lane);
  run_layer(ahi, alo, pack, UB_L1, 8, b1, wc, lm, lg, lane);
  run_layer(ahi, alo, pack, UB_L2, 8, b2, wc, lm, lg, lane);
  run_layer(ahi, alo, pack, UB_L3, 8, b3, wc, lm, lg, lane);

  // ---------------- final layer: 256 -> 1 (vectorized dot) ----------------
  {
    int pl = tid >> 3, q = tid & 7;   // 8 threads/point, 32 elems each
    const unsigned short* hrow = ahi + pl * LDA + (q << 5);
    const unsigned short* lrow = alo + pl * LDA + (q << 5);
    const float* w4p = W4 + (q << 5);
    float sum = 0.0f;
#pragma unroll
    for (int c = 0; c < 4; ++c) {
      u32x4 th = *(const u32x4*)(hrow + (c << 3));
      u32x4 tl = *(const u32x4*)(lrow + (c << 3));
      float4 wA = *(const float4*)(w4p + (c << 3));
      float4 wB = *(const float4*)(w4p + (c << 3) + 4);
#pragma unroll
      for (int e = 0; e < 4; ++e) {
        unsigned hu = th[e >> 1], lu = tl[e >> 1];
        unsigned sh = (e & 1) << 4;
        float v = bf16_bits_to_f32((hu >> sh) & 0xffffu) + bf16_bits_to_f32((lu >> sh) & 0xffffu);
        sum = fmaf(v, (&wA.x)[e], sum);
      }
#pragma unroll
      for (int e = 0; e < 4; ++e) {
        unsigned hu = th[2 + (e >> 1)], lu = tl[2 + (e >> 1)];
        unsigned sh = (e & 1) << 4;
        float v = bf16_bits_to_f32((hu >> sh) & 0xffffu) + bf16_bits_to_f32((lu >> sh) & 0xffffu);
        sum = fmaf(v, (&wB.x)[e], sum);
      }
    }
    sum += __shfl_xor(sum, 1);
    sum += __shfl_xor(sum, 2);
    sum += __shfl_xor(sum, 4);
    if (q == 0) out[(size_t)blockIdx.x * MTILE + pl] = sum + b4[0];
  }
}

// ------------------------------- launcher ----------------------------------
extern "C" void kernel_launch(void* const* d_in, const int* in_sizes, int n_in,
                              void* d_out, int out_size, void* d_ws, size_t ws_size,
                              hipStream_t stream) {
  const float* x      = (const float*)d_in[0];
  const float* tables = (const float*)d_in[1];
  const float* W0 = (const float*)d_in[2];  const float* b0 = (const float*)d_in[3];
  const float* W1 = (const float*)d_in[4];  const float* b1 = (const float*)d_in[5];
  const float* W2 = (const float*)d_in[6];  const float* b2 = (const float*)d_in[7];
  const float* W3 = (const float*)d_in[8];  const float* b3 = (const float*)d_in[9];
  const float* W4 = (const float*)d_in[10]; const float* b4 = (const float*)d_in[11];
  unsigned short* pack = (unsigned short*)d_ws;
  float* out = (float*)d_out;

  // replicate numpy's level params with host libm doubles
  LevelParams P;
  double bgrow = exp((log(512.0) - log(8.0)) / 15.0);
  for (int l = 0; l < 16; ++l) {
    double r = floor(8.0 * pow(bgrow, (double)l));
    P.res[l] = (float)r;
    double hsd = r * r;
    if (hsd > 4096.0) hsd = 4096.0;
    P.hsize[l] = (unsigned)hsd;
  }

  prep_pack<<<UNITS_TOTAL, 64, 0, stream>>>(W0, W1, W2, W3, pack);

  size_t smem_bytes = (size_t)ACT_ELEMS * 2 * 2;  // 67584
  hipFuncSetAttribute(reinterpret_cast<const void*>(inr_main),
                      hipFuncAttributeMaxDynamicSharedMemorySize, (int)smem_bytes);

  int nblocks = out_size / MTILE;  // 262144/64 = 4096
  inr_main<<<nblocks, 512, smem_bytes, stream>>>(x, tables, b0, b1, b2, b3, W4, b4,
                                                 pack, out, P);
}

// Round 3
// 287.747 us; speedup vs baseline: 1.0684x; 1.0017x over previous
//
#include <hip/hip_runtime.h>
#include <math.h>

// ---------------------------------------------------------------------------
// HashGrid INR fused kernel for MI355X (gfx950) — round 3
//   - template-unrolled K loop (software-pipelined weight/LDS loads)
//   - magic-number modulo in encode (no fp-division sequences)
//   - truncation-split epilogue/encode (half the VALU of RNE splitting)
// ---------------------------------------------------------------------------

typedef __bf16 bf16x8 __attribute__((ext_vector_type(8)));
typedef float  f32x4  __attribute__((ext_vector_type(4)));
typedef unsigned int u32x4 __attribute__((ext_vector_type(4)));
typedef unsigned int u32x2 __attribute__((ext_vector_type(2)));

struct LevelParams {
  float res[16];
  unsigned hsize[16];
  unsigned M[8];     // magic multiplier for levels 0..7
  unsigned c16[8];   // 65536 % d
  int      sh[8];    // post-mulhi shift
};

static constexpr int MTILE = 64;         // points per block
static constexpr int LDA   = 264;        // padded activation row stride (elems)
static constexpr int ACT_ELEMS = MTILE * LDA;   // 16896
static constexpr int UNITS_L0 = 32;
static constexpr int UB_L0 = 0, UB_L1 = 32, UB_L2 = 160, UB_L3 = 288;
static constexpr int UNITS_TOTAL = 416;

__device__ __forceinline__ unsigned short f32_to_bf16_rne(float f) {
  unsigned u = __float_as_uint(f);
  unsigned r = (u + 0x7fffu + ((u >> 16) & 1u)) >> 16;
  return (unsigned short)r;
}
__device__ __forceinline__ float bf16_bits_to_f32(unsigned u16bits) {
  return __uint_as_float(u16bits << 16);
}

// pack hi bf16 of (v0,v1) -> u32 (trunc); compiler fuses to v_perm
__device__ __forceinline__ unsigned pack_hi(unsigned u0, unsigned u1) {
  return (u0 >> 16) | (u1 & 0xffff0000u);
}

// --------------------------- weight packing --------------------------------
// unit (kstep s, coltile ct): [2][64 lanes][8 elems] bf16; hi@lane*8+e, lo@512+...
// mapping: out-col = 16*ct + (lane&15), k = 32*s + 8*(lane>>4) + e
__global__ void prep_pack(const float* __restrict__ W0, const float* __restrict__ W1,
                          const float* __restrict__ W2, const float* __restrict__ W3,
                          unsigned short* __restrict__ pack) {
  int b = blockIdx.x;
  int lane = threadIdx.x;
  const float* W; int K; int r;
  if (b < UNITS_L0) { W = W0; K = 33; r = b; }
  else {
    int b2 = b - UNITS_L0; int ly = b2 >> 7; r = b2 & 127;
    W = (ly == 0) ? W1 : (ly == 1) ? W2 : W3; K = 256;
  }
  int s = r >> 4, ct = r & 15;
  int col   = (ct << 4) + (lane & 15);
  int kbase = (s << 5) + ((lane >> 4) << 3);
  unsigned short* dst = pack + (size_t)b * 1024;
#pragma unroll
  for (int e = 0; e < 8; ++e) {
    int k = kbase + e;
    float v = (k < K) ? W[k * 256 + col] : 0.0f;
    unsigned u = __float_as_uint(v);
    unsigned short h = (unsigned short)(u >> 16);           // truncation hi
    float hf = bf16_bits_to_f32(u >> 16);
    unsigned short lo = f32_to_bf16_rne(v - hf);
    dst[lane * 8 + e]       = h;
    dst[512 + lane * 8 + e] = lo;
  }
}

// ------------------------------ layer body ---------------------------------
// wave wc: cols [wc*32, wc*32+32), all 64 points. A=weights, B=activations.
// D: col(lane&15)=point, row(4*(lane>>4)+r)=out col.
template<int S>
__device__ __forceinline__ void run_layer(unsigned short* __restrict__ ahi,
                                          unsigned short* __restrict__ alo,
                                          const unsigned short* __restrict__ pack,
                                          int unitbase,
                                          const float* __restrict__ bias,
                                          int wc, int lm, int lg, int lane) {
  f32x4 acc[4][2];
#pragma unroll
  for (int i = 0; i < 4; ++i)
#pragma unroll
    for (int j = 0; j < 2; ++j) acc[i][j] = (f32x4)0.0f;

#pragma unroll
  for (int s = 0; s < S; ++s) {
    bf16x8 w_h[2], w_l[2];
#pragma unroll
    for (int ct = 0; ct < 2; ++ct) {
      const unsigned short* bp =
          pack + (size_t)(unitbase + (s << 4) + (wc << 1) + ct) * 1024 + (lane << 3);
      w_h[ct] = __builtin_bit_cast(bf16x8, *(const u32x4*)(bp));
      w_l[ct] = __builtin_bit_cast(bf16x8, *(const u32x4*)(bp + 512));
    }
#pragma unroll
    for (int pt = 0; pt < 4; ++pt) {
      int off = ((pt << 4) + lm) * LDA + (s << 5) + (lg << 3);
      bf16x8 a_h = __builtin_bit_cast(bf16x8, *(const u32x4*)(ahi + off));
      bf16x8 a_l = __builtin_bit_cast(bf16x8, *(const u32x4*)(alo + off));
      acc[pt][0] = __builtin_amdgcn_mfma_f32_16x16x32_bf16(w_h[0], a_h, acc[pt][0], 0, 0, 0);
      acc[pt][1] = __builtin_amdgcn_mfma_f32_16x16x32_bf16(w_h[1], a_h, acc[pt][1], 0, 0, 0);
      acc[pt][0] = __builtin_amdgcn_mfma_f32_16x16x32_bf16(w_l[0], a_h, acc[pt][0], 0, 0, 0);
      acc[pt][1] = __builtin_amdgcn_mfma_f32_16x16x32_bf16(w_l[1], a_h, acc[pt][1], 0, 0, 0);
      acc[pt][0] = __builtin_amdgcn_mfma_f32_16x16x32_bf16(w_h[0], a_l, acc[pt][0], 0, 0, 0);
      acc[pt][1] = __builtin_amdgcn_mfma_f32_16x16x32_bf16(w_h[1], a_l, acc[pt][1], 0, 0, 0);
    }
  }
  __syncthreads();   // all reads of act done -> safe to overwrite
#pragma unroll
  for (int pt = 0; pt < 4; ++pt)
#pragma unroll
    for (int ct = 0; ct < 2; ++ct) {
      int colbase = (((wc << 1) + ct) << 4) + (lg << 2);
      float4 bv = *(const float4*)(bias + colbase);
      int base = ((pt << 4) + lm) * LDA + colbase;
      float v0 = fmaxf(acc[pt][ct][0] + bv.x, 0.0f);
      float v1 = fmaxf(acc[pt][ct][1] + bv.y, 0.0f);
      float v2 = fmaxf(acc[pt][ct][2] + bv.z, 0.0f);
      float v3 = fmaxf(acc[pt][ct][3] + bv.w, 0.0f);
      unsigned u0 = __float_as_uint(v0), u1 = __float_as_uint(v1);
      unsigned u2 = __float_as_uint(v2), u3 = __float_as_uint(v3);
      u32x2 hw = { pack_hi(u0, u1), pack_hi(u2, u3) };
      // truncation lo (error <= 2^-16 rel; v >= 0 post-ReLU)
      float l0 = v0 - __uint_as_float(u0 & 0xffff0000u);
      float l1 = v1 - __uint_as_float(u1 & 0xffff0000u);
      float l2 = v2 - __uint_as_float(u2 & 0xffff0000u);
      float l3 = v3 - __uint_as_float(u3 & 0xffff0000u);
      u32x2 lw = { pack_hi(__float_as_uint(l0), __float_as_uint(l1)),
                   pack_hi(__float_as_uint(l2), __float_as_uint(l3)) };
      *(u32x2*)(ahi + base) = hw;
      *(u32x2*)(alo + base) = lw;
    }
  __syncthreads();
}

// ------------------------------ main kernel --------------------------------
__global__ __launch_bounds__(512, 4) void inr_main(
    const float* __restrict__ x, const float* __restrict__ tables,
    const float* __restrict__ b0, const float* __restrict__ b1,
    const float* __restrict__ b2, const float* __restrict__ b3,
    const float* __restrict__ W4, const float* __restrict__ b4,
    const unsigned short* __restrict__ pack, float* __restrict__ out,
    LevelParams P) {
  extern __shared__ char smem[];
  unsigned short* ahi = (unsigned short*)smem;
  unsigned short* alo = ahi + ACT_ELEMS;

  const int tid = threadIdx.x;

  // -------- encode: 8 threads/point; thread q does level q (magic) + q+8 (AND)
  {
    int pl = tid >> 3, q = tid & 7;
    size_t p = (size_t)blockIdx.x * MTILE + pl;
    float x0 = x[3 * p + 0], x1 = x[3 * p + 1], x2 = x[3 * p + 2];
    float f_lo0, f_lo1, f_hi0, f_hi1;

    // level q: hashed with exact magic modulo
    {
      float rf = P.res[q];
      unsigned d = P.hsize[q], c = P.c16[q], M = P.M[q];
      int sh = P.sh[q];
      float xs0 = x0 * rf, xs1 = x1 * rf;
      float fl0 = floorf(xs0), fl1 = floorf(xs1);
      float f0 = xs0 - fl0, f1 = xs1 - fl1;
      int i0 = (int)fl0, i1 = (int)fl1;
      unsigned ua0 = (unsigned)i0, ua1 = (unsigned)(i0 + 1);
      unsigned vb0 = (unsigned)i1 * 2654435761u;
      unsigned vb1 = (unsigned)(i1 + 1) * 2654435761u;
      const float* tl = tables + ((size_t)q << 13);
      float g0 = 1.0f - f0, g1 = 1.0f - f1;
      unsigned e0 = ua0 ^ vb0, e1 = ua0 ^ vb1, e2 = ua1 ^ vb0, e3 = ua1 ^ vb1;
      // fold to < 65536*d, then magic: exact n % d for all u32 n
      unsigned n0 = (e0 >> 16) * c + (e0 & 0xffffu);
      unsigned n1 = (e1 >> 16) * c + (e1 & 0xffffu);
      unsigned n2 = (e2 >> 16) * c + (e2 & 0xffffu);
      unsigned n3 = (e3 >> 16) * c + (e3 & 0xffffu);
      unsigned h0 = n0 - (__umulhi(n0, M) >> sh) * d;
      unsigned h1 = n1 - (__umulhi(n1, M) >> sh) * d;
      unsigned h2 = n2 - (__umulhi(n2, M) >> sh) * d;
      unsigned h3 = n3 - (__umulhi(n3, M) >> sh) * d;
      float a0 = 0.0f, a1 = 0.0f;
      { float w = g0 * g1; a0 += w * tl[2*h0]; a1 += w * tl[2*h0+1]; }
      { float w = g0 * f1; a0 += w * tl[2*h1]; a1 += w * tl[2*h1+1]; }
      { float w = f0 * g1; a0 += w * tl[2*h2]; a1 += w * tl[2*h2+1]; }
      { float w = f0 * f1; a0 += w * tl[2*h3]; a1 += w * tl[2*h3+1]; }
      f_lo0 = a0; f_lo1 = a1;
    }
    // level q+8: hsize == 4096 -> AND
    {
      int l = q + 8;
      float rf = P.res[l];
      float xs0 = x0 * rf, xs1 = x1 * rf;
      float fl0 = floorf(xs0), fl1 = floorf(xs1);
      float f0 = xs0 - fl0, f1 = xs1 - fl1;
      int i0 = (int)fl0, i1 = (int)fl1;
      unsigned ua0 = (unsigned)i0, ua1 = (unsigned)(i0 + 1);
      unsigned vb0 = (unsigned)i1 * 2654435761u;
      unsigned vb1 = (unsigned)(i1 + 1) * 2654435761u;
      const float* tl = tables + ((size_t)l << 13);
      float g0 = 1.0f - f0, g1 = 1.0f - f1;
      unsigned h0 = (ua0 ^ vb0) & 4095u, h1 = (ua0 ^ vb1) & 4095u;
      unsigned h2 = (ua1 ^ vb0) & 4095u, h3 = (ua1 ^ vb1) & 4095u;
      float a0 = 0.0f, a1 = 0.0f;
      { float w = g0 * g1; a0 += w * tl[2*h0]; a1 += w * tl[2*h0+1]; }
      { float w = g0 * f1; a0 += w * tl[2*h1]; a1 += w * tl[2*h1+1]; }
      { float w = f0 * g1; a0 += w * tl[2*h2]; a1 += w * tl[2*h2+1]; }
      { float w = f0 * f1; a0 += w * tl[2*h3]; a1 += w * tl[2*h3+1]; }
      f_hi0 = a0; f_hi1 = a1;
    }
    // store: level q -> cols {2q,2q+1}; level q+8 -> cols {16+2q,16+2q+1}
    {
      int rowb = pl * LDA;
      unsigned u0 = __float_as_uint(f_lo0), u1 = __float_as_uint(f_lo1);
      unsigned u2 = __float_as_uint(f_hi0), u3 = __float_as_uint(f_hi1);
      float l0 = f_lo0 - __uint_as_float(u0 & 0xffff0000u);
      float l1 = f_lo1 - __uint_as_float(u1 & 0xffff0000u);
      float l2 = f_hi0 - __uint_as_float(u2 & 0xffff0000u);
      float l3 = f_hi1 - __uint_as_float(u3 & 0xffff0000u);
      *(unsigned*)(ahi + rowb + 2*q)      = pack_hi(u0, u1);
      *(unsigned*)(ahi + rowb + 16 + 2*q) = pack_hi(u2, u3);
      *(unsigned*)(alo + rowb + 2*q)      = pack_hi(__float_as_uint(l0), __float_as_uint(l1));
      *(unsigned*)(alo + rowb + 16 + 2*q) = pack_hi(__float_as_uint(l2), __float_as_uint(l3));
    }
    // tail cols 32+4q..35+4q: [x2, 0, 0, ...]
    {
      int base = pl * LDA + 32 + (q << 2);
      if (q == 0) {
        unsigned u0 = __float_as_uint(x2);
        float l0 = x2 - __uint_as_float(u0 & 0xffff0000u);
        u32x2 hw = { u0 >> 16, 0u };
        u32x2 lw = { __float_as_uint(l0) >> 16, 0u };
        *(u32x2*)(ahi + base) = hw;
        *(u32x2*)(alo + base) = lw;
      } else {
        u32x2 z = { 0u, 0u };
        *(u32x2*)(ahi + base) = z;
        *(u32x2*)(alo + base) = z;
      }
    }
  }
  __syncthreads();

  const int lane = tid & 63;
  const int wc = tid >> 6;
  const int lm = lane & 15, lg = lane >> 4;

  run_layer<2>(ahi, alo, pack, UB_L0, b0, wc, lm, lg, lane);
  run_layer<8>(ahi, alo, pack, UB_L1, b1, wc, lm, lg, lane);
  run_layer<8>(ahi, alo, pack, UB_L2, b2, wc, lm, lg, lane);
  run_layer<8>(ahi, alo, pack, UB_L3, b3, wc, lm, lg, lane);

  // ---------------- final layer: 256 -> 1 (vectorized dot) ----------------
  {
    int pl = tid >> 3, q = tid & 7;
    const unsigned short* hrow = ahi + pl * LDA + (q << 5);
    const unsigned short* lrow = alo + pl * LDA + (q << 5);
    const float* w4p = W4 + (q << 5);
    float sum = 0.0f;
#pragma unroll
    for (int c = 0; c < 4; ++c) {
      u32x4 th = *(const u32x4*)(hrow + (c << 3));
      u32x4 tl = *(const u32x4*)(lrow + (c << 3));
      float4 wA = *(const float4*)(w4p + (c << 3));
      float4 wB = *(const float4*)(w4p + (c << 3) + 4);
#pragma unroll
      for (int u = 0; u < 4; ++u) {
        unsigned hu = th[u], lu = tl[u];
        float v0 = __uint_as_float(hu << 16) + __uint_as_float(lu << 16);
        float v1 = __uint_as_float(hu & 0xffff0000u) + __uint_as_float(lu & 0xffff0000u);
        const float* wp = (u < 2) ? &wA.x : &wB.x;
        int base = (u & 1) << 1;
        sum = fmaf(v0, wp[base], sum);
        sum = fmaf(v1, wp[base + 1], sum);
      }
    }
    sum += __shfl_xor(sum, 1);
    sum += __shfl_xor(sum, 2);
    sum += __shfl_xor(sum, 4);
    if (q == 0) out[(size_t)blockIdx.x * MTILE + pl] = sum + b4[0];
  }
}

// ------------------------------- launcher ----------------------------------
extern "C" void kernel_launch(void* const* d_in, const int* in_sizes, int n_in,
                              void* d_out, int out_size, void* d_ws, size_t ws_size,
                              hipStream_t stream) {
  const float* x      = (const float*)d_in[0];
  const float* tables = (const float*)d_in[1];
  const float* W0 = (const float*)d_in[2];  const float* b0 = (const float*)d_in[3];
  const float* W1 = (const float*)d_in[4];  const float* b1 = (const float*)d_in[5];
  const float* W2 = (const float*)d_in[6];  const float* b2 = (const float*)d_in[7];
  const float* W3 = (const float*)d_in[8];  const float* b3 = (const float*)d_in[9];
  const float* W4 = (const float*)d_in[10]; const float* b4 = (const float*)d_in[11];
  unsigned short* pack = (unsigned short*)d_ws;
  float* out = (float*)d_out;

  LevelParams P;
  double bgrow = exp((log(512.0) - log(8.0)) / 15.0);
  for (int l = 0; l < 16; ++l) {
    double r = floor(8.0 * pow(bgrow, (double)l));
    P.res[l] = (float)r;
    double hsd = r * r;
    if (hsd > 4096.0) hsd = 4096.0;
    P.hsize[l] = (unsigned)hsd;
  }
  // magic modulo for levels 0..7: n' = (n>>16)*c16 + (n&0xffff)  (n' ≡ n mod d,
  // n' <= 65535*d); q = mulhi(n',M)>>sh exact since n'max*d < 2^(32+sh).
  for (int l = 0; l < 8; ++l) {
    unsigned d = P.hsize[l];
    P.c16[l] = 65536u % d;
    unsigned long long nmax = 65535ULL * d;
    int s = 0;
    while (nmax * d >= (1ULL << (32 + s))) s++;
    P.sh[l] = s;
    P.M[l] = (unsigned)((1ULL << (32 + s)) / d + 1);
  }

  prep_pack<<<UNITS_TOTAL, 64, 0, stream>>>(W0, W1, W2, W3, pack);

  size_t smem_bytes = (size_t)ACT_ELEMS * 2 * 2;  // 67584
  hipFuncSetAttribute(reinterpret_cast<const void*>(inr_main),
                      hipFuncAttributeMaxDynamicSharedMemorySize, (int)smem_bytes);

  int nblocks = out_size / MTILE;  // 4096
  inr_main<<<nblocks, 512, smem_bytes, stream>>>(x, tables, b0, b1, b2, b3, W4, b4,
                                                 pack, out, P);
}